// Round 2
// baseline (602.213 us; speedup 1.0000x reference)
//
#include <hip/hip_runtime.h>
#include <hip/hip_bf16.h>
#include <math.h>

#define NEG_SLOPE 0.2f
#define EPS_F 1e-16f

// ---------------- edge dtype detection ----------------
// If edge_index is int64 (little-endian, values < 2^31, nonneg), every odd
// 32-bit word is a zero hi-word. If int32, odd words are random node ids.
__global__ void k_detect(const unsigned int* __restrict__ eidx, int* flag) {
    int t = threadIdx.x;                 // 64 threads = 1 wave
    unsigned int v = eidx[2 * t + 1];    // words 1,3,...,127 (< 1KB, in bounds)
    #pragma unroll
    for (int m = 1; m <= 32; m <<= 1) v |= __shfl_xor(v, m);
    if (t == 0) *flag = (v == 0u) ? 1 : 0;   // 1 => int64
}

__global__ void k_convert(const unsigned int* __restrict__ eidx,
                          const int* __restrict__ flag,
                          int* __restrict__ src32, int* __restrict__ dst32, int E) {
    int e = blockIdx.x * blockDim.x + threadIdx.x;
    if (e >= E) return;
    if (*flag) {
        src32[e] = (int)eidx[2 * e];
        dst32[e] = (int)eidx[2 * (E + e)];
    } else {
        src32[e] = (int)eidx[e];
        dst32[e] = (int)eidx[E + e];
    }
}

// ---------------- f32 GEMM: h = x @ W  (K=128, Ncols=128) ----------------
#define GR 64   // rows per block
#define KC 32   // k-chunk
__global__ __launch_bounds__(256)
void k_gemm(const float* __restrict__ x, const float* __restrict__ W,
            float* __restrict__ h, int N) {
    __shared__ float xs[GR * 33];     // [row][k] stride 33 (bank-friendly)
    __shared__ float Ws[KC * 128];    // [k][c] with XOR bit-swizzle on c

    int t  = threadIdx.x;
    int br = blockIdx.x * GR;
    int rg = t >> 4, cg = t & 15;
    int r0 = rg * 4, c0 = cg * 8;
    int f5 = ((c0 >> 5) & 1) << 2;    // swizzle flip for this column block
    int sA = c0 ^ f5;                 // LDS addr of group holding W[c0..c0+3]
    int sB = (c0 + 4) ^ f5;           // LDS addr of group holding W[c0+4..c0+7]

    float acc[4][8];
    #pragma unroll
    for (int i = 0; i < 4; i++)
        #pragma unroll
        for (int j = 0; j < 8; j++) acc[i][j] = 0.f;

    for (int kk0 = 0; kk0 < 128; kk0 += KC) {
        __syncthreads();
        // stage W chunk (32x128 = 1024 float4), swizzled store
        #pragma unroll
        for (int i = 0; i < 4; i++) {
            int f   = t + i * 256;
            int row = f >> 5;
            int c4  = (f & 31) << 2;
            int cs  = c4 ^ (((c4 >> 5) & 1) << 2);
            float4 v = *(const float4*)&W[(kk0 + row) * 128 + c4];
            *(float4*)&Ws[row * 128 + cs] = v;
        }
        // stage x chunk (64 rows x 32 k) into stride-33 tile
        #pragma unroll
        for (int i = 0; i < 2; i++) {
            int f   = t + i * 256;
            int row = f >> 3;
            int c4  = (f & 7) << 2;
            int gr_ = br + row;
            float4 v = make_float4(0.f, 0.f, 0.f, 0.f);
            if (gr_ < N) v = *(const float4*)&x[gr_ * 128 + kk0 + c4];
            xs[row * 33 + c4 + 0] = v.x;
            xs[row * 33 + c4 + 1] = v.y;
            xs[row * 33 + c4 + 2] = v.z;
            xs[row * 33 + c4 + 3] = v.w;
        }
        __syncthreads();
        #pragma unroll
        for (int kk = 0; kk < KC; kk++) {
            float4 w0 = *(const float4*)&Ws[kk * 128 + sA];
            float4 w1 = *(const float4*)&Ws[kk * 128 + sB];
            float wv[8] = {w0.x, w0.y, w0.z, w0.w, w1.x, w1.y, w1.z, w1.w};
            float xv[4];
            #pragma unroll
            for (int i = 0; i < 4; i++) xv[i] = xs[(r0 + i) * 33 + kk];
            #pragma unroll
            for (int i = 0; i < 4; i++)
                #pragma unroll
                for (int j = 0; j < 8; j++)
                    acc[i][j] = fmaf(xv[i], wv[j], acc[i][j]);
        }
    }
    #pragma unroll
    for (int i = 0; i < 4; i++) {
        int r = br + r0 + i;
        if (r < N) {
            *(float4*)&h[r * 128 + c0]     = make_float4(acc[i][0], acc[i][1], acc[i][2], acc[i][3]);
            *(float4*)&h[r * 128 + c0 + 4] = make_float4(acc[i][4], acc[i][5], acc[i][6], acc[i][7]);
        }
    }
}

// ---------------- per-node attention logits ----------------
__global__ void k_logits(const float* __restrict__ h,
                         const float* __restrict__ att_src,
                         const float* __restrict__ att_dst,
                         float* __restrict__ a_src, float* __restrict__ a_dst, int N) {
    int wave = threadIdx.x >> 6;
    int lane = threadIdx.x & 63;
    int n = blockIdx.x * 4 + wave;
    if (n >= N) return;
    float2 hv  = *(const float2*)&h[n * 128 + lane * 2];
    float2 asv = *(const float2*)&att_src[lane * 2];
    float2 adv = *(const float2*)&att_dst[lane * 2];
    float ps = hv.x * asv.x + hv.y * asv.y;
    float pd = hv.x * adv.x + hv.y * adv.y;
    #pragma unroll
    for (int m = 1; m < 16; m <<= 1) {
        ps += __shfl_xor(ps, m);
        pd += __shfl_xor(pd, m);
    }
    if ((lane & 15) == 0) {
        int head = lane >> 4;
        a_src[n * 4 + head] = ps;
        a_dst[n * 4 + head] = pd;
    }
}

// ---------------- per-edge softmax weights + denominators ----------------
__global__ void k_edge_w(const int* __restrict__ src32, const int* __restrict__ dst32,
                         const float* __restrict__ a_src, const float* __restrict__ a_dst,
                         float* __restrict__ w, float* __restrict__ denom, int E, int N) {
    int e = blockIdx.x * blockDim.x + threadIdx.x;
    int M = E + N;
    if (e >= M) return;
    int s, d;
    if (e < E) { s = src32[e]; d = dst32[e]; }
    else       { s = e - E;    d = s; }
    float4 as = *(const float4*)&a_src[s * 4];
    float4 ad = *(const float4*)&a_dst[d * 4];
    float ev[4] = {as.x + ad.x, as.y + ad.y, as.z + ad.z, as.w + ad.w};
    #pragma unroll
    for (int i = 0; i < 4; i++) {
        float v = ev[i];
        v = (v >= 0.f) ? v : NEG_SLOPE * v;
        ev[i] = __expf(v);
    }
    *(float4*)&w[e * 4] = make_float4(ev[0], ev[1], ev[2], ev[3]);
    atomicAdd(&denom[d * 4 + 0], ev[0]);
    atomicAdd(&denom[d * 4 + 1], ev[1]);
    atomicAdd(&denom[d * 4 + 2], ev[2]);
    atomicAdd(&denom[d * 4 + 3], ev[3]);
}

// ---------------- weighted scatter-aggregate ----------------
__global__ void k_scatter(const int* __restrict__ src32, const int* __restrict__ dst32,
                          const float* __restrict__ w, const float* __restrict__ denom,
                          const float* __restrict__ h, float* __restrict__ out,
                          int E, int N) {
    unsigned int gid = blockIdx.x * blockDim.x + threadIdx.x;
    unsigned int e = gid >> 7;
    int c = gid & 127;
    if (e >= (unsigned int)(E + N)) return;
    int s, d;
    if (e < (unsigned int)E) { s = src32[e]; d = dst32[e]; }
    else                     { s = (int)e - E; d = s; }
    int hd = c >> 5;
    float alpha = w[e * 4 + hd] / (denom[d * 4 + hd] + EPS_F);
    atomicAdd(&out[d * 128 + c], alpha * h[s * 128 + c]);
}

// ---------------- finalize: out = relu(out + bias) ----------------
__global__ void k_finalize(float* __restrict__ out, const float* __restrict__ bias, int total4) {
    int i = blockIdx.x * blockDim.x + threadIdx.x;
    if (i >= total4) return;
    float4 v = ((float4*)out)[i];
    int cb = (i & 31) << 2;
    float4 b = *(const float4*)&bias[cb];
    v.x = fmaxf(v.x + b.x, 0.f);
    v.y = fmaxf(v.y + b.y, 0.f);
    v.z = fmaxf(v.z + b.z, 0.f);
    v.w = fmaxf(v.w + b.w, 0.f);
    ((float4*)out)[i] = v;
}

extern "C" void kernel_launch(void* const* d_in, const int* in_sizes, int n_in,
                              void* d_out, int out_size, void* d_ws, size_t ws_size,
                              hipStream_t stream) {
    const float* x        = (const float*)d_in[0];
    const unsigned int* e = (const unsigned int*)d_in[1];
    const float* W        = (const float*)d_in[2];
    const float* att_src  = (const float*)d_in[3];
    const float* att_dst  = (const float*)d_in[4];
    const float* bias     = (const float*)d_in[5];
    float* out            = (float*)d_out;

    int N = in_sizes[0] / 128;
    int E = in_sizes[1] / 2;
    int M = E + N;

    char* ws = (char*)d_ws;
    size_t off = 0;
    int*   flag  = (int*)(ws + off);  off += 256;
    int*   src32 = (int*)(ws + off);  off += (size_t)E * 4;
    int*   dst32 = (int*)(ws + off);  off += (size_t)E * 4;
    float* h     = (float*)(ws + off); off += (size_t)N * 128 * 4;
    float* a_src = (float*)(ws + off); off += (size_t)N * 16;
    float* a_dst = (float*)(ws + off); off += (size_t)N * 16;
    float* wbuf  = (float*)(ws + off); off += (size_t)M * 16;
    float* denom = (float*)(ws + off); off += (size_t)N * 16;

    hipMemsetAsync(out, 0, (size_t)N * 128 * 4, stream);
    hipMemsetAsync(denom, 0, (size_t)N * 16, stream);

    k_detect<<<1, 64, 0, stream>>>(e, flag);
    k_convert<<<(E + 255) / 256, 256, 0, stream>>>(e, flag, src32, dst32, E);
    k_gemm<<<(N + GR - 1) / GR, 256, 0, stream>>>(x, W, h, N);
    k_logits<<<(N + 3) / 4, 256, 0, stream>>>(h, att_src, att_dst, a_src, a_dst, N);
    k_edge_w<<<(M + 255) / 256, 256, 0, stream>>>(src32, dst32, a_src, a_dst, wbuf, denom, E, N);
    {
        long long total = (long long)M * 128;
        int blocks = (int)((total + 255) / 256);
        k_scatter<<<blocks, 256, 0, stream>>>(src32, dst32, wbuf, denom, h, out, E, N);
    }
    k_finalize<<<(N * 32 + 255) / 256, 256, 0, stream>>>(out, bias, N * 32);
}

// Round 3
// 393.086 us; speedup vs baseline: 1.5320x; 1.5320x over previous
//
#include <hip/hip_runtime.h>
#include <hip/hip_bf16.h>
#include <math.h>

#define NEG_SLOPE 0.2f
#define EPS_F 1e-16f

// ---------------- edge dtype detection ----------------
__global__ void k_detect(const unsigned int* __restrict__ eidx, int* flag) {
    int t = threadIdx.x;
    unsigned int v = eidx[2 * t + 1];
    #pragma unroll
    for (int m = 1; m <= 32; m <<= 1) v |= __shfl_xor(v, m);
    if (t == 0) *flag = (v == 0u) ? 1 : 0;   // 1 => int64
}

// convert to int32 src/dst + build dst histogram (real edges only)
__global__ void k_convert_hist(const unsigned int* __restrict__ eidx,
                               const int* __restrict__ flag,
                               int* __restrict__ src32, int* __restrict__ dst32,
                               int* __restrict__ deg, int E) {
    int e = blockIdx.x * blockDim.x + threadIdx.x;
    if (e >= E) return;
    int s, d;
    if (*flag) {
        s = (int)eidx[2 * e];
        d = (int)eidx[2 * (E + e)];
    } else {
        s = (int)eidx[e];
        d = (int)eidx[E + e];
    }
    src32[e] = s;
    dst32[e] = d;
    atomicAdd(&deg[d], 1);
}

// ---------------- f32 GEMM: h = x @ W  (K=128, Ncols=128) ----------------
#define GR 64
#define KC 32
__global__ __launch_bounds__(256)
void k_gemm(const float* __restrict__ x, const float* __restrict__ W,
            float* __restrict__ h, int N) {
    __shared__ float xs[GR * 33];
    __shared__ float Ws[KC * 128];

    int t  = threadIdx.x;
    int br = blockIdx.x * GR;
    int rg = t >> 4, cg = t & 15;
    int r0 = rg * 4, c0 = cg * 8;
    int f5 = ((c0 >> 5) & 1) << 2;
    int sA = c0 ^ f5;
    int sB = (c0 + 4) ^ f5;

    float acc[4][8];
    #pragma unroll
    for (int i = 0; i < 4; i++)
        #pragma unroll
        for (int j = 0; j < 8; j++) acc[i][j] = 0.f;

    for (int kk0 = 0; kk0 < 128; kk0 += KC) {
        __syncthreads();
        #pragma unroll
        for (int i = 0; i < 4; i++) {
            int f   = t + i * 256;
            int row = f >> 5;
            int c4  = (f & 31) << 2;
            int cs  = c4 ^ (((c4 >> 5) & 1) << 2);
            float4 v = *(const float4*)&W[(kk0 + row) * 128 + c4];
            *(float4*)&Ws[row * 128 + cs] = v;
        }
        #pragma unroll
        for (int i = 0; i < 2; i++) {
            int f   = t + i * 256;
            int row = f >> 3;
            int c4  = (f & 7) << 2;
            int gr_ = br + row;
            float4 v = make_float4(0.f, 0.f, 0.f, 0.f);
            if (gr_ < N) v = *(const float4*)&x[gr_ * 128 + kk0 + c4];
            xs[row * 33 + c4 + 0] = v.x;
            xs[row * 33 + c4 + 1] = v.y;
            xs[row * 33 + c4 + 2] = v.z;
            xs[row * 33 + c4 + 3] = v.w;
        }
        __syncthreads();
        #pragma unroll
        for (int kk = 0; kk < KC; kk++) {
            float4 w0 = *(const float4*)&Ws[kk * 128 + sA];
            float4 w1 = *(const float4*)&Ws[kk * 128 + sB];
            float wv[8] = {w0.x, w0.y, w0.z, w0.w, w1.x, w1.y, w1.z, w1.w};
            float xv[4];
            #pragma unroll
            for (int i = 0; i < 4; i++) xv[i] = xs[(r0 + i) * 33 + kk];
            #pragma unroll
            for (int i = 0; i < 4; i++)
                #pragma unroll
                for (int j = 0; j < 8; j++)
                    acc[i][j] = fmaf(xv[i], wv[j], acc[i][j]);
        }
    }
    #pragma unroll
    for (int i = 0; i < 4; i++) {
        int r = br + r0 + i;
        if (r < N) {
            *(float4*)&h[r * 128 + c0]     = make_float4(acc[i][0], acc[i][1], acc[i][2], acc[i][3]);
            *(float4*)&h[r * 128 + c0 + 4] = make_float4(acc[i][4], acc[i][5], acc[i][6], acc[i][7]);
        }
    }
}

// ---------------- per-node attention logits ----------------
__global__ void k_logits(const float* __restrict__ h,
                         const float* __restrict__ att_src,
                         const float* __restrict__ att_dst,
                         float* __restrict__ a_src, float* __restrict__ a_dst, int N) {
    int wave = threadIdx.x >> 6;
    int lane = threadIdx.x & 63;
    int n = blockIdx.x * 4 + wave;
    if (n >= N) return;
    float2 hv  = *(const float2*)&h[n * 128 + lane * 2];
    float2 asv = *(const float2*)&att_src[lane * 2];
    float2 adv = *(const float2*)&att_dst[lane * 2];
    float ps = hv.x * asv.x + hv.y * asv.y;
    float pd = hv.x * adv.x + hv.y * adv.y;
    #pragma unroll
    for (int m = 1; m < 16; m <<= 1) {
        ps += __shfl_xor(ps, m);
        pd += __shfl_xor(pd, m);
    }
    if ((lane & 15) == 0) {
        int head = lane >> 4;
        a_src[n * 4 + head] = ps;
        a_dst[n * 4 + head] = pd;
    }
}

// ---------------- exclusive scan of deg -> row (3 kernels) ----------------
// scan1: 1024 elems/block (256 thr x 4), exclusive within block + block sums
__global__ __launch_bounds__(256)
void k_scan1(const int* __restrict__ deg, int* __restrict__ row,
             int* __restrict__ bsum, int N) {
    __shared__ int ts[256];
    int t = threadIdx.x;
    int base = blockIdx.x * 1024 + t * 4;
    int v0 = (base + 0 < N) ? deg[base + 0] : 0;
    int v1 = (base + 1 < N) ? deg[base + 1] : 0;
    int v2 = (base + 2 < N) ? deg[base + 2] : 0;
    int v3 = (base + 3 < N) ? deg[base + 3] : 0;
    int s = v0 + v1 + v2 + v3;
    ts[t] = s;
    __syncthreads();
    // Hillis-Steele inclusive scan over 256 thread sums
    #pragma unroll
    for (int off = 1; off < 256; off <<= 1) {
        int u = (t >= off) ? ts[t - off] : 0;
        __syncthreads();
        ts[t] += u;
        __syncthreads();
    }
    int excl = ts[t] - s;
    if (t == 255) bsum[blockIdx.x] = ts[255];
    if (base + 0 < N) row[base + 0] = excl;
    if (base + 1 < N) row[base + 1] = excl + v0;
    if (base + 2 < N) row[base + 2] = excl + v0 + v1;
    if (base + 3 < N) row[base + 3] = excl + v0 + v1 + v2;
}

// scan2: single wave scans block sums (nb <= 64) -> exclusive
__global__ void k_scan2(int* __restrict__ bsum, int nb) {
    int t = threadIdx.x;
    int v = (t < nb) ? bsum[t] : 0;
    int orig = v;
    #pragma unroll
    for (int off = 1; off < 64; off <<= 1) {
        int u = __shfl_up(v, off);
        if (t >= off) v += u;
    }
    if (t < nb) bsum[t] = v - orig;
}

__global__ void k_scan3(int* __restrict__ row, const int* __restrict__ bsum, int N) {
    int i = blockIdx.x * blockDim.x + threadIdx.x;
    if (i >= N) return;
    row[i] += bsum[i >> 10];
}

// ---------------- edge weights + denom + bucket fill ----------------
__global__ void k_edge_fill(const int* __restrict__ src32, const int* __restrict__ dst32,
                            const float* __restrict__ a_src, const float* __restrict__ a_dst,
                            const int* __restrict__ row, int* __restrict__ cur,
                            int* __restrict__ bsrc, float4* __restrict__ bw,
                            float* __restrict__ denom, int E, int N) {
    int e = blockIdx.x * blockDim.x + threadIdx.x;
    int M = E + N;
    if (e >= M) return;
    int s, d;
    if (e < E) { s = src32[e]; d = dst32[e]; }
    else       { s = e - E;    d = s; }
    float4 as = *(const float4*)&a_src[s * 4];
    float4 ad = *(const float4*)&a_dst[d * 4];
    float ev[4] = {as.x + ad.x, as.y + ad.y, as.z + ad.z, as.w + ad.w};
    #pragma unroll
    for (int i = 0; i < 4; i++) {
        float v = ev[i];
        v = (v >= 0.f) ? v : NEG_SLOPE * v;
        ev[i] = __expf(v);
    }
    atomicAdd(&denom[d * 4 + 0], ev[0]);
    atomicAdd(&denom[d * 4 + 1], ev[1]);
    atomicAdd(&denom[d * 4 + 2], ev[2]);
    atomicAdd(&denom[d * 4 + 3], ev[3]);
    if (e < E) {
        int pos = row[d] + atomicAdd(&cur[d], 1);
        bsrc[pos] = s;
        bw[pos] = make_float4(ev[0], ev[1], ev[2], ev[3]);
    }
    // self-loop weight recomputed in k_aggregate; denom already includes it
}

// ---------------- gather-side aggregation: one wave per dst node ----------------
__global__ __launch_bounds__(256)
void k_aggregate(const int* __restrict__ bsrc, const float* __restrict__ bw,
                 const int* __restrict__ row, const int* __restrict__ deg,
                 const float* __restrict__ a_src, const float* __restrict__ a_dst,
                 const float* __restrict__ denom, const float* __restrict__ h,
                 const float* __restrict__ bias, float* __restrict__ out, int N) {
    int wave = threadIdx.x >> 6;
    int lane = threadIdx.x & 63;
    int d = blockIdx.x * 4 + wave;
    if (d >= N) return;
    int c0 = lane * 2;
    int head = lane >> 4;

    // self-loop contribution
    float es = a_src[d * 4 + head] + a_dst[d * 4 + head];
    es = (es >= 0.f) ? es : NEG_SLOPE * es;
    float wself = __expf(es);
    float2 hv = *(const float2*)&h[d * 128 + c0];
    float accx = wself * hv.x;
    float accy = wself * hv.y;

    int start = row[d];
    int g = deg[d];
    for (int j = start; j < start + g; j++) {
        int s = bsrc[j];                       // same addr across wave -> 1 line
        float wv = bw[j * 4 + head];           // 4 distinct addrs in 1 line
        float2 hs = *(const float2*)&h[s * 128 + c0];
        accx = fmaf(wv, hs.x, accx);
        accy = fmaf(wv, hs.y, accy);
    }
    float rden = 1.f / (denom[d * 4 + head] + EPS_F);
    float2 b2 = *(const float2*)&bias[c0];
    float ox = fmaxf(accx * rden + b2.x, 0.f);
    float oy = fmaxf(accy * rden + b2.y, 0.f);
    *(float2*)&out[d * 128 + c0] = make_float2(ox, oy);
}

extern "C" void kernel_launch(void* const* d_in, const int* in_sizes, int n_in,
                              void* d_out, int out_size, void* d_ws, size_t ws_size,
                              hipStream_t stream) {
    const float* x        = (const float*)d_in[0];
    const unsigned int* e = (const unsigned int*)d_in[1];
    const float* W        = (const float*)d_in[2];
    const float* att_src  = (const float*)d_in[3];
    const float* att_dst  = (const float*)d_in[4];
    const float* bias     = (const float*)d_in[5];
    float* out            = (float*)d_out;

    int N = in_sizes[0] / 128;
    int E = in_sizes[1] / 2;
    int M = E + N;

    char* ws = (char*)d_ws;
    size_t off = 0;
    int*    flag  = (int*)(ws + off);   off += 256;
    int*    src32 = (int*)(ws + off);   off += (size_t)E * 4;
    int*    dst32 = (int*)(ws + off);   off += (size_t)E * 4;
    float*  h     = (float*)(ws + off); off += (size_t)N * 128 * 4;
    float*  a_src = (float*)(ws + off); off += (size_t)N * 16;
    float*  a_dst = (float*)(ws + off); off += (size_t)N * 16;
    float*  denom = (float*)(ws + off); off += (size_t)N * 16;
    int*    deg   = (int*)(ws + off);   off += (size_t)N * 4;
    int*    cur   = (int*)(ws + off);   off += (size_t)N * 4;
    int*    row   = (int*)(ws + off);   off += (size_t)N * 4;
    int*    bsum  = (int*)(ws + off);   off += 4096;
    int*    bsrc  = (int*)(ws + off);   off += (size_t)E * 4;
    float4* bw    = (float4*)(ws + off); off += (size_t)E * 16;

    int nb = (N + 1023) / 1024;

    hipMemsetAsync(deg,   0, (size_t)N * 4,  stream);
    hipMemsetAsync(cur,   0, (size_t)N * 4,  stream);
    hipMemsetAsync(denom, 0, (size_t)N * 16, stream);

    k_detect<<<1, 64, 0, stream>>>(e, flag);
    k_convert_hist<<<(E + 255) / 256, 256, 0, stream>>>(e, flag, src32, dst32, deg, E);
    k_gemm<<<(N + GR - 1) / GR, 256, 0, stream>>>(x, W, h, N);
    k_logits<<<(N + 3) / 4, 256, 0, stream>>>(h, att_src, att_dst, a_src, a_dst, N);
    k_scan1<<<nb, 256, 0, stream>>>(deg, row, bsum, N);
    k_scan2<<<1, 64, 0, stream>>>(bsum, nb);
    k_scan3<<<(N + 255) / 256, 256, 0, stream>>>(row, bsum, N);
    k_edge_fill<<<(M + 255) / 256, 256, 0, stream>>>(src32, dst32, a_src, a_dst,
                                                     row, cur, bsrc, (float4*)bw, denom, E, N);
    k_aggregate<<<(N + 3) / 4, 256, 0, stream>>>(bsrc, (const float*)bw, row, deg,
                                                 a_src, a_dst, denom, h, bias, out, N);
}

// Round 4
// 178.394 us; speedup vs baseline: 3.3757x; 2.2035x over previous
//
#include <hip/hip_runtime.h>
#include <hip/hip_bf16.h>
#include <math.h>

#define NEG_SLOPE 0.2f
#define EPS_F 1e-16f

// ---------------- edge dtype detection ----------------
__global__ void k_detect(const unsigned int* __restrict__ eidx, int* flag) {
    int t = threadIdx.x;
    unsigned int v = eidx[2 * t + 1];
    #pragma unroll
    for (int m = 1; m <= 32; m <<= 1) v |= __shfl_xor(v, m);
    if (t == 0) *flag = (v == 0u) ? 1 : 0;   // 1 => int64
}

// convert to int32 src/dst + dst histogram; remember each edge's slot in its bucket
__global__ void k_convert_hist(const unsigned int* __restrict__ eidx,
                               const int* __restrict__ flag,
                               int* __restrict__ src32, int* __restrict__ dst32,
                               int* __restrict__ rel, int* __restrict__ deg, int E) {
    int e = blockIdx.x * blockDim.x + threadIdx.x;
    if (e >= E) return;
    int s, d;
    if (*flag) {
        s = (int)eidx[2 * e];
        d = (int)eidx[2 * (E + e)];
    } else {
        s = (int)eidx[e];
        d = (int)eidx[E + e];
    }
    src32[e] = s;
    dst32[e] = d;
    rel[e] = atomicAdd(&deg[d], 1);
}

// ---------------- f32 GEMM: h = x @ W  (K=128, Ncols=128) ----------------
#define GR 64
#define KC 32
__global__ __launch_bounds__(256)
void k_gemm(const float* __restrict__ x, const float* __restrict__ W,
            float* __restrict__ h, int N) {
    __shared__ float xs[GR * 33];
    __shared__ float Ws[KC * 128];

    int t  = threadIdx.x;
    int br = blockIdx.x * GR;
    int rg = t >> 4, cg = t & 15;
    int r0 = rg * 4, c0 = cg * 8;
    int f5 = ((c0 >> 5) & 1) << 2;
    int sA = c0 ^ f5;
    int sB = (c0 + 4) ^ f5;

    float acc[4][8];
    #pragma unroll
    for (int i = 0; i < 4; i++)
        #pragma unroll
        for (int j = 0; j < 8; j++) acc[i][j] = 0.f;

    for (int kk0 = 0; kk0 < 128; kk0 += KC) {
        __syncthreads();
        #pragma unroll
        for (int i = 0; i < 4; i++) {
            int f   = t + i * 256;
            int row = f >> 5;
            int c4  = (f & 31) << 2;
            int cs  = c4 ^ (((c4 >> 5) & 1) << 2);
            float4 v = *(const float4*)&W[(kk0 + row) * 128 + c4];
            *(float4*)&Ws[row * 128 + cs] = v;
        }
        #pragma unroll
        for (int i = 0; i < 2; i++) {
            int f   = t + i * 256;
            int row = f >> 3;
            int c4  = (f & 7) << 2;
            int gr_ = br + row;
            float4 v = make_float4(0.f, 0.f, 0.f, 0.f);
            if (gr_ < N) v = *(const float4*)&x[gr_ * 128 + kk0 + c4];
            xs[row * 33 + c4 + 0] = v.x;
            xs[row * 33 + c4 + 1] = v.y;
            xs[row * 33 + c4 + 2] = v.z;
            xs[row * 33 + c4 + 3] = v.w;
        }
        __syncthreads();
        #pragma unroll
        for (int kk = 0; kk < KC; kk++) {
            float4 w0 = *(const float4*)&Ws[kk * 128 + sA];
            float4 w1 = *(const float4*)&Ws[kk * 128 + sB];
            float wv[8] = {w0.x, w0.y, w0.z, w0.w, w1.x, w1.y, w1.z, w1.w};
            float xv[4];
            #pragma unroll
            for (int i = 0; i < 4; i++) xv[i] = xs[(r0 + i) * 33 + kk];
            #pragma unroll
            for (int i = 0; i < 4; i++)
                #pragma unroll
                for (int j = 0; j < 8; j++)
                    acc[i][j] = fmaf(xv[i], wv[j], acc[i][j]);
        }
    }
    #pragma unroll
    for (int i = 0; i < 4; i++) {
        int r = br + r0 + i;
        if (r < N) {
            *(float4*)&h[r * 128 + c0]     = make_float4(acc[i][0], acc[i][1], acc[i][2], acc[i][3]);
            *(float4*)&h[r * 128 + c0 + 4] = make_float4(acc[i][4], acc[i][5], acc[i][6], acc[i][7]);
        }
    }
}

// ---------------- per-node attention logits ----------------
__global__ void k_logits(const float* __restrict__ h,
                         const float* __restrict__ att_src,
                         const float* __restrict__ att_dst,
                         float* __restrict__ a_src, float* __restrict__ a_dst, int N) {
    int wave = threadIdx.x >> 6;
    int lane = threadIdx.x & 63;
    int n = blockIdx.x * 4 + wave;
    if (n >= N) return;
    float2 hv  = *(const float2*)&h[n * 128 + lane * 2];
    float2 asv = *(const float2*)&att_src[lane * 2];
    float2 adv = *(const float2*)&att_dst[lane * 2];
    float ps = hv.x * asv.x + hv.y * asv.y;
    float pd = hv.x * adv.x + hv.y * adv.y;
    #pragma unroll
    for (int m = 1; m < 16; m <<= 1) {
        ps += __shfl_xor(ps, m);
        pd += __shfl_xor(pd, m);
    }
    if ((lane & 15) == 0) {
        int head = lane >> 4;
        a_src[n * 4 + head] = ps;
        a_dst[n * 4 + head] = pd;
    }
}

// ---------------- exclusive scan of deg -> row ----------------
__global__ __launch_bounds__(256)
void k_scan1(const int* __restrict__ deg, int* __restrict__ row,
             int* __restrict__ bsum, int N) {
    __shared__ int ts[256];
    int t = threadIdx.x;
    int base = blockIdx.x * 1024 + t * 4;
    int v0 = (base + 0 < N) ? deg[base + 0] : 0;
    int v1 = (base + 1 < N) ? deg[base + 1] : 0;
    int v2 = (base + 2 < N) ? deg[base + 2] : 0;
    int v3 = (base + 3 < N) ? deg[base + 3] : 0;
    int s = v0 + v1 + v2 + v3;
    ts[t] = s;
    __syncthreads();
    #pragma unroll
    for (int off = 1; off < 256; off <<= 1) {
        int u = (t >= off) ? ts[t - off] : 0;
        __syncthreads();
        ts[t] += u;
        __syncthreads();
    }
    int excl = ts[t] - s;
    if (t == 255) bsum[blockIdx.x] = ts[255];
    if (base + 0 < N) row[base + 0] = excl;
    if (base + 1 < N) row[base + 1] = excl + v0;
    if (base + 2 < N) row[base + 2] = excl + v0 + v1;
    if (base + 3 < N) row[base + 3] = excl + v0 + v1 + v2;
}

__global__ void k_scan2(int* __restrict__ bsum, int nb) {
    int t = threadIdx.x;
    int v = (t < nb) ? bsum[t] : 0;
    int orig = v;
    #pragma unroll
    for (int off = 1; off < 64; off <<= 1) {
        int u = __shfl_up(v, off);
        if (t >= off) v += u;
    }
    if (t < nb) bsum[t] = v - orig;
}

__global__ void k_scan3(int* __restrict__ row, const int* __restrict__ bsum, int N) {
    int i = blockIdx.x * blockDim.x + threadIdx.x;
    if (i >= N) return;
    row[i] += bsum[i >> 10];
}

// ---------------- bucket fill (no atomics) ----------------
__global__ void k_fill(const int* __restrict__ src32, const int* __restrict__ dst32,
                       const int* __restrict__ rel, const int* __restrict__ row,
                       int* __restrict__ bsrc, int E) {
    int e = blockIdx.x * blockDim.x + threadIdx.x;
    if (e >= E) return;
    bsrc[row[dst32[e]] + rel[e]] = src32[e];
}

// ---------------- fused gather aggregation: one wave per dst node ----------------
// Recomputes edge weights on the fly; accumulates numerator and denominator
// in one pass. alpha = w_e / (sum_w + EPS) with unshifted exp (|logit| <~ 12,
// no overflow in f32; identical to the reference softmax up to rounding).
__global__ __launch_bounds__(256)
void k_aggregate(const int* __restrict__ bsrc, const int* __restrict__ row,
                 const int* __restrict__ deg,
                 const float* __restrict__ a_src, const float* __restrict__ a_dst,
                 const float* __restrict__ h, const float* __restrict__ bias,
                 float* __restrict__ out, int N) {
    int wave = threadIdx.x >> 6;
    int lane = threadIdx.x & 63;
    int d = blockIdx.x * 4 + wave;
    if (d >= N) return;
    int c0 = lane * 2;
    int head = lane >> 4;

    float ad = a_dst[d * 4 + head];

    // self-loop contribution
    float es = a_src[d * 4 + head] + ad;
    es = (es >= 0.f) ? es : NEG_SLOPE * es;
    float wself = __expf(es);
    float2 hv = *(const float2*)&h[d * 128 + c0];
    float accx = wself * hv.x;
    float accy = wself * hv.y;
    float den  = wself;

    int start = row[d];
    int end   = start + deg[d];
    int j = start;
    for (; j + 1 < end; j += 2) {
        int s0 = bsrc[j];
        int s1 = bsrc[j + 1];
        float as0 = a_src[s0 * 4 + head];
        float as1 = a_src[s1 * 4 + head];
        float2 h0 = *(const float2*)&h[s0 * 128 + c0];
        float2 h1 = *(const float2*)&h[s1 * 128 + c0];
        float e0 = as0 + ad; e0 = (e0 >= 0.f) ? e0 : NEG_SLOPE * e0;
        float e1 = as1 + ad; e1 = (e1 >= 0.f) ? e1 : NEG_SLOPE * e1;
        float w0 = __expf(e0);
        float w1 = __expf(e1);
        den += w0 + w1;
        accx = fmaf(w0, h0.x, accx);
        accy = fmaf(w0, h0.y, accy);
        accx = fmaf(w1, h1.x, accx);
        accy = fmaf(w1, h1.y, accy);
    }
    if (j < end) {
        int s0 = bsrc[j];
        float as0 = a_src[s0 * 4 + head];
        float2 h0 = *(const float2*)&h[s0 * 128 + c0];
        float e0 = as0 + ad; e0 = (e0 >= 0.f) ? e0 : NEG_SLOPE * e0;
        float w0 = __expf(e0);
        den += w0;
        accx = fmaf(w0, h0.x, accx);
        accy = fmaf(w0, h0.y, accy);
    }

    float rden = 1.f / (den + EPS_F);
    float2 b2 = *(const float2*)&bias[c0];
    float ox = fmaxf(accx * rden + b2.x, 0.f);
    float oy = fmaxf(accy * rden + b2.y, 0.f);
    *(float2*)&out[d * 128 + c0] = make_float2(ox, oy);
}

extern "C" void kernel_launch(void* const* d_in, const int* in_sizes, int n_in,
                              void* d_out, int out_size, void* d_ws, size_t ws_size,
                              hipStream_t stream) {
    const float* x        = (const float*)d_in[0];
    const unsigned int* e = (const unsigned int*)d_in[1];
    const float* W        = (const float*)d_in[2];
    const float* att_src  = (const float*)d_in[3];
    const float* att_dst  = (const float*)d_in[4];
    const float* bias     = (const float*)d_in[5];
    float* out            = (float*)d_out;

    int N = in_sizes[0] / 128;
    int E = in_sizes[1] / 2;

    char* ws = (char*)d_ws;
    size_t off = 0;
    int*    flag  = (int*)(ws + off);   off += 256;
    int*    src32 = (int*)(ws + off);   off += (size_t)E * 4;
    int*    dst32 = (int*)(ws + off);   off += (size_t)E * 4;
    int*    rel   = (int*)(ws + off);   off += (size_t)E * 4;
    float*  h     = (float*)(ws + off); off += (size_t)N * 128 * 4;
    float*  a_src = (float*)(ws + off); off += (size_t)N * 16;
    float*  a_dst = (float*)(ws + off); off += (size_t)N * 16;
    int*    deg   = (int*)(ws + off);   off += (size_t)N * 4;
    int*    row   = (int*)(ws + off);   off += (size_t)N * 4;
    int*    bsum  = (int*)(ws + off);   off += 4096;
    int*    bsrc  = (int*)(ws + off);   off += (size_t)E * 4;

    int nb = (N + 1023) / 1024;

    hipMemsetAsync(deg, 0, (size_t)N * 4, stream);

    k_detect<<<1, 64, 0, stream>>>(e, flag);
    k_convert_hist<<<(E + 255) / 256, 256, 0, stream>>>(e, flag, src32, dst32, rel, deg, E);
    k_gemm<<<(N + GR - 1) / GR, 256, 0, stream>>>(x, W, h, N);
    k_logits<<<(N + 3) / 4, 256, 0, stream>>>(h, att_src, att_dst, a_src, a_dst, N);
    k_scan1<<<nb, 256, 0, stream>>>(deg, row, bsum, N);
    k_scan2<<<1, 64, 0, stream>>>(bsum, nb);
    k_scan3<<<(N + 255) / 256, 256, 0, stream>>>(row, bsum, N);
    k_fill<<<(E + 255) / 256, 256, 0, stream>>>(src32, dst32, rel, row, bsrc, E);
    k_aggregate<<<(N + 3) / 4, 256, 0, stream>>>(bsrc, row, deg, a_src, a_dst, h, bias, out, N);
}

// Round 5
// 154.539 us; speedup vs baseline: 3.8968x; 1.1544x over previous
//
#include <hip/hip_runtime.h>
#include <hip/hip_bf16.h>
#include <math.h>

#define NEG_SLOPE 0.2f
#define EPS_F 1e-16f

__device__ __forceinline__ unsigned int pk2bf(float a, float b) {
    unsigned int ua = __float_as_uint(a), ub = __float_as_uint(b);
    ua = (ua + 0x7fffu + ((ua >> 16) & 1u)) >> 16;
    ub = (ub + 0x7fffu + ((ub >> 16) & 1u)) >> 16;
    return ua | (ub << 16);
}
__device__ __forceinline__ float bf_lo(unsigned int p) { return __uint_as_float(p << 16); }
__device__ __forceinline__ float bf_hi(unsigned int p) { return __uint_as_float(p & 0xffff0000u); }

// ---------------- edge dtype detection ----------------
__global__ void k_detect(const unsigned int* __restrict__ eidx, int* flag) {
    int t = threadIdx.x;
    unsigned int v = eidx[2 * t + 1];
    #pragma unroll
    for (int m = 1; m <= 32; m <<= 1) v |= __shfl_xor(v, m);
    if (t == 0) *flag = (v == 0u) ? 1 : 0;   // 1 => int64
}

// convert to int32 src/dst + dst histogram; remember each edge's slot
__global__ void k_convert_hist(const unsigned int* __restrict__ eidx,
                               const int* __restrict__ flag,
                               int* __restrict__ src32, int* __restrict__ dst32,
                               int* __restrict__ rel, int* __restrict__ deg, int E) {
    int e = blockIdx.x * blockDim.x + threadIdx.x;
    if (e >= E) return;
    int s, d;
    if (*flag) {
        s = (int)eidx[2 * e];
        d = (int)eidx[2 * (E + e)];
    } else {
        s = (int)eidx[e];
        d = (int)eidx[E + e];
    }
    src32[e] = s;
    dst32[e] = d;
    rel[e] = atomicAdd(&deg[d], 1);
}

// ---------------- f32 GEMM: h = x @ W, fused logits + bf16 h output ----------------
#define GR 64
#define KC 32
__global__ __launch_bounds__(256)
void k_gemm(const float* __restrict__ x, const float* __restrict__ W,
            const float* __restrict__ att_src, const float* __restrict__ att_dst,
            unsigned short* __restrict__ hb,
            float* __restrict__ a_src, float* __restrict__ a_dst, int N) {
    __shared__ float xs[GR * 33];
    __shared__ float Ws[KC * 128];

    int t  = threadIdx.x;
    int br = blockIdx.x * GR;
    int rg = t >> 4, cg = t & 15;
    int r0 = rg * 4, c0 = cg * 8;
    int f5 = ((c0 >> 5) & 1) << 2;
    int sA = c0 ^ f5;
    int sB = (c0 + 4) ^ f5;

    float acc[4][8];
    #pragma unroll
    for (int i = 0; i < 4; i++)
        #pragma unroll
        for (int j = 0; j < 8; j++) acc[i][j] = 0.f;

    for (int kk0 = 0; kk0 < 128; kk0 += KC) {
        __syncthreads();
        #pragma unroll
        for (int i = 0; i < 4; i++) {
            int f   = t + i * 256;
            int row = f >> 5;
            int c4  = (f & 31) << 2;
            int cs  = c4 ^ (((c4 >> 5) & 1) << 2);
            float4 v = *(const float4*)&W[(kk0 + row) * 128 + c4];
            *(float4*)&Ws[row * 128 + cs] = v;
        }
        #pragma unroll
        for (int i = 0; i < 2; i++) {
            int f   = t + i * 256;
            int row = f >> 3;
            int c4  = (f & 7) << 2;
            int gr_ = br + row;
            float4 v = make_float4(0.f, 0.f, 0.f, 0.f);
            if (gr_ < N) v = *(const float4*)&x[gr_ * 128 + kk0 + c4];
            xs[row * 33 + c4 + 0] = v.x;
            xs[row * 33 + c4 + 1] = v.y;
            xs[row * 33 + c4 + 2] = v.z;
            xs[row * 33 + c4 + 3] = v.w;
        }
        __syncthreads();
        #pragma unroll
        for (int kk = 0; kk < KC; kk++) {
            float4 w0 = *(const float4*)&Ws[kk * 128 + sA];
            float4 w1 = *(const float4*)&Ws[kk * 128 + sB];
            float wv[8] = {w0.x, w0.y, w0.z, w0.w, w1.x, w1.y, w1.z, w1.w};
            float xv[4];
            #pragma unroll
            for (int i = 0; i < 4; i++) xv[i] = xs[(r0 + i) * 33 + kk];
            #pragma unroll
            for (int i = 0; i < 4; i++)
                #pragma unroll
                for (int j = 0; j < 8; j++)
                    acc[i][j] = fmaf(xv[i], wv[j], acc[i][j]);
        }
    }

    // per-thread att vectors for its 8 columns (all within one head)
    float ats[8], atd[8];
    #pragma unroll
    for (int j = 0; j < 8; j++) {
        ats[j] = att_src[c0 + j];
        atd[j] = att_dst[c0 + j];
    }
    int head = c0 >> 5;

    #pragma unroll
    for (int i = 0; i < 4; i++) {
        int r = br + r0 + i;
        // logit partials over this thread's 8 cols
        float ps = 0.f, pd = 0.f;
        #pragma unroll
        for (int j = 0; j < 8; j++) {
            ps = fmaf(acc[i][j], ats[j], ps);
            pd = fmaf(acc[i][j], atd[j], pd);
        }
        // reduce across the 4 lanes covering this head (lanes t, t^1, t^2)
        ps += __shfl_xor(ps, 1); ps += __shfl_xor(ps, 2);
        pd += __shfl_xor(pd, 1); pd += __shfl_xor(pd, 2);
        if (r < N) {
            if ((t & 3) == 0) {
                a_src[r * 4 + head] = ps;
                a_dst[r * 4 + head] = pd;
            }
            // bf16 h store: 8 cols -> 16B
            uint4 pk;
            pk.x = pk2bf(acc[i][0], acc[i][1]);
            pk.y = pk2bf(acc[i][2], acc[i][3]);
            pk.z = pk2bf(acc[i][4], acc[i][5]);
            pk.w = pk2bf(acc[i][6], acc[i][7]);
            *(uint4*)&hb[r * 128 + c0] = pk;
        }
    }
}

// ---------------- exclusive scan of deg -> row ----------------
__global__ __launch_bounds__(256)
void k_scan1(const int* __restrict__ deg, int* __restrict__ row,
             int* __restrict__ bsum, int N) {
    __shared__ int ts[256];
    int t = threadIdx.x;
    int base = blockIdx.x * 1024 + t * 4;
    int v0 = (base + 0 < N) ? deg[base + 0] : 0;
    int v1 = (base + 1 < N) ? deg[base + 1] : 0;
    int v2 = (base + 2 < N) ? deg[base + 2] : 0;
    int v3 = (base + 3 < N) ? deg[base + 3] : 0;
    int s = v0 + v1 + v2 + v3;
    ts[t] = s;
    __syncthreads();
    #pragma unroll
    for (int off = 1; off < 256; off <<= 1) {
        int u = (t >= off) ? ts[t - off] : 0;
        __syncthreads();
        ts[t] += u;
        __syncthreads();
    }
    int excl = ts[t] - s;
    if (t == 255) bsum[blockIdx.x] = ts[255];
    if (base + 0 < N) row[base + 0] = excl;
    if (base + 1 < N) row[base + 1] = excl + v0;
    if (base + 2 < N) row[base + 2] = excl + v0 + v1;
    if (base + 3 < N) row[base + 3] = excl + v0 + v1 + v2;
}

__global__ void k_scan2(int* __restrict__ bsum, int nb) {
    int t = threadIdx.x;
    int v = (t < nb) ? bsum[t] : 0;
    int orig = v;
    #pragma unroll
    for (int off = 1; off < 64; off <<= 1) {
        int u = __shfl_up(v, off);
        if (t >= off) v += u;
    }
    if (t < nb) bsum[t] = v - orig;
}

__global__ void k_scan3(int* __restrict__ row, const int* __restrict__ bsum, int N) {
    int i = blockIdx.x * blockDim.x + threadIdx.x;
    if (i >= N) return;
    row[i] += bsum[i >> 10];
}

// ---------------- bucket fill (no atomics) ----------------
__global__ void k_fill(const int* __restrict__ src32, const int* __restrict__ dst32,
                       const int* __restrict__ rel, const int* __restrict__ row,
                       int* __restrict__ bsrc, int E) {
    int e = blockIdx.x * blockDim.x + threadIdx.x;
    if (e >= E) return;
    bsrc[row[dst32[e]] + rel[e]] = src32[e];
}

// ---------------- fused gather aggregation: one wave per dst node ----------------
__global__ __launch_bounds__(256)
void k_aggregate(const int* __restrict__ bsrc, const int* __restrict__ row,
                 const int* __restrict__ deg,
                 const float* __restrict__ a_src, const float* __restrict__ a_dst,
                 const unsigned short* __restrict__ hb,
                 const float* __restrict__ bias,
                 float* __restrict__ out, int N) {
    int wave = threadIdx.x >> 6;
    int lane = threadIdx.x & 63;
    int d = blockIdx.x * 4 + wave;
    if (d >= N) return;
    int c0 = lane * 2;
    int head = lane >> 4;

    float ad = a_dst[d * 4 + head];

    // self-loop contribution
    float es = a_src[d * 4 + head] + ad;
    es = (es >= 0.f) ? es : NEG_SLOPE * es;
    float wself = __expf(es);
    unsigned int hp = *(const unsigned int*)&hb[d * 128 + c0];
    float accx = wself * bf_lo(hp);
    float accy = wself * bf_hi(hp);
    float den  = wself;

    int start = row[d];
    int end   = start + deg[d];
    int j = start;
    for (; j + 3 < end; j += 4) {
        int s0 = bsrc[j + 0];
        int s1 = bsrc[j + 1];
        int s2 = bsrc[j + 2];
        int s3 = bsrc[j + 3];
        float as0 = a_src[s0 * 4 + head];
        float as1 = a_src[s1 * 4 + head];
        float as2 = a_src[s2 * 4 + head];
        float as3 = a_src[s3 * 4 + head];
        unsigned int p0 = *(const unsigned int*)&hb[s0 * 128 + c0];
        unsigned int p1 = *(const unsigned int*)&hb[s1 * 128 + c0];
        unsigned int p2 = *(const unsigned int*)&hb[s2 * 128 + c0];
        unsigned int p3 = *(const unsigned int*)&hb[s3 * 128 + c0];
        float e0 = as0 + ad; e0 = (e0 >= 0.f) ? e0 : NEG_SLOPE * e0;
        float e1 = as1 + ad; e1 = (e1 >= 0.f) ? e1 : NEG_SLOPE * e1;
        float e2 = as2 + ad; e2 = (e2 >= 0.f) ? e2 : NEG_SLOPE * e2;
        float e3 = as3 + ad; e3 = (e3 >= 0.f) ? e3 : NEG_SLOPE * e3;
        float w0 = __expf(e0), w1 = __expf(e1), w2 = __expf(e2), w3 = __expf(e3);
        den += (w0 + w1) + (w2 + w3);
        accx = fmaf(w0, bf_lo(p0), accx);
        accy = fmaf(w0, bf_hi(p0), accy);
        accx = fmaf(w1, bf_lo(p1), accx);
        accy = fmaf(w1, bf_hi(p1), accy);
        accx = fmaf(w2, bf_lo(p2), accx);
        accy = fmaf(w2, bf_hi(p2), accy);
        accx = fmaf(w3, bf_lo(p3), accx);
        accy = fmaf(w3, bf_hi(p3), accy);
    }
    for (; j < end; j++) {
        int s0 = bsrc[j];
        float as0 = a_src[s0 * 4 + head];
        unsigned int p0 = *(const unsigned int*)&hb[s0 * 128 + c0];
        float e0 = as0 + ad; e0 = (e0 >= 0.f) ? e0 : NEG_SLOPE * e0;
        float w0 = __expf(e0);
        den += w0;
        accx = fmaf(w0, bf_lo(p0), accx);
        accy = fmaf(w0, bf_hi(p0), accy);
    }

    float rden = 1.f / (den + EPS_F);
    float2 b2 = *(const float2*)&bias[c0];
    float ox = fmaxf(accx * rden + b2.x, 0.f);
    float oy = fmaxf(accy * rden + b2.y, 0.f);
    *(float2*)&out[d * 128 + c0] = make_float2(ox, oy);
}

extern "C" void kernel_launch(void* const* d_in, const int* in_sizes, int n_in,
                              void* d_out, int out_size, void* d_ws, size_t ws_size,
                              hipStream_t stream) {
    const float* x        = (const float*)d_in[0];
    const unsigned int* e = (const unsigned int*)d_in[1];
    const float* W        = (const float*)d_in[2];
    const float* att_src  = (const float*)d_in[3];
    const float* att_dst  = (const float*)d_in[4];
    const float* bias     = (const float*)d_in[5];
    float* out            = (float*)d_out;

    int N = in_sizes[0] / 128;
    int E = in_sizes[1] / 2;

    char* ws = (char*)d_ws;
    size_t off = 0;
    int*            flag  = (int*)(ws + off);            off += 256;
    int*            src32 = (int*)(ws + off);            off += (size_t)E * 4;
    int*            dst32 = (int*)(ws + off);            off += (size_t)E * 4;
    int*            rel   = (int*)(ws + off);            off += (size_t)E * 4;
    unsigned short* hb    = (unsigned short*)(ws + off); off += (size_t)N * 128 * 2;
    float*          a_src = (float*)(ws + off);          off += (size_t)N * 16;
    float*          a_dst = (float*)(ws + off);          off += (size_t)N * 16;
    int*            deg   = (int*)(ws + off);            off += (size_t)N * 4;
    int*            row   = (int*)(ws + off);            off += (size_t)N * 4;
    int*            bsum  = (int*)(ws + off);            off += 4096;
    int*            bsrc  = (int*)(ws + off);            off += (size_t)E * 4;

    int nb = (N + 1023) / 1024;

    hipMemsetAsync(deg, 0, (size_t)N * 4, stream);

    k_detect<<<1, 64, 0, stream>>>(e, flag);
    k_convert_hist<<<(E + 255) / 256, 256, 0, stream>>>(e, flag, src32, dst32, rel, deg, E);
    k_gemm<<<(N + GR - 1) / GR, 256, 0, stream>>>(x, W, att_src, att_dst, hb, a_src, a_dst, N);
    k_scan1<<<nb, 256, 0, stream>>>(deg, row, bsum, N);
    k_scan2<<<1, 64, 0, stream>>>(bsum, nb);
    k_scan3<<<(N + 255) / 256, 256, 0, stream>>>(row, bsum, N);
    k_fill<<<(E + 255) / 256, 256, 0, stream>>>(src32, dst32, rel, row, bsrc, E);
    k_aggregate<<<(N + 3) / 4, 256, 0, stream>>>(bsrc, row, deg, a_src, a_dst, hb, bias, out, N);
}

// Round 6
// 137.536 us; speedup vs baseline: 4.3786x; 1.1236x over previous
//
#include <hip/hip_runtime.h>
#include <hip/hip_bf16.h>
#include <math.h>

#define NEG_SLOPE 0.2f
#define EPS_F 1e-16f

typedef float f32x4 __attribute__((ext_vector_type(4)));
typedef short bf16x8 __attribute__((ext_vector_type(8)));

__device__ __forceinline__ unsigned int pk2bf(float a, float b) {
    unsigned int ua = __float_as_uint(a), ub = __float_as_uint(b);
    ua = (ua + 0x7fffu + ((ua >> 16) & 1u)) >> 16;
    ub = (ub + 0x7fffu + ((ub >> 16) & 1u)) >> 16;
    return ua | (ub << 16);
}
__device__ __forceinline__ unsigned short f2bf(float f) {
    unsigned int u = __float_as_uint(f);
    return (unsigned short)((u + 0x7fffu + ((u >> 16) & 1u)) >> 16);
}
__device__ __forceinline__ float bf_lo(unsigned int p) { return __uint_as_float(p << 16); }
__device__ __forceinline__ float bf_hi(unsigned int p) { return __uint_as_float(p & 0xffff0000u); }

// ---------------- edge dtype detection ----------------
__global__ void k_detect(const unsigned int* __restrict__ eidx, int* flag) {
    int t = threadIdx.x;
    unsigned int v = eidx[2 * t + 1];
    #pragma unroll
    for (int m = 1; m <= 32; m <<= 1) v |= __shfl_xor(v, m);
    if (t == 0) *flag = (v == 0u) ? 1 : 0;   // 1 => int64
}

// convert to int32 src/dst + dst histogram; remember each edge's slot
__global__ void k_convert_hist(const unsigned int* __restrict__ eidx,
                               const int* __restrict__ flag,
                               int* __restrict__ src32, int* __restrict__ dst32,
                               int* __restrict__ rel, int* __restrict__ deg, int E) {
    int e = blockIdx.x * blockDim.x + threadIdx.x;
    if (e >= E) return;
    int s, d;
    if (*flag) {
        s = (int)eidx[2 * e];
        d = (int)eidx[2 * (E + e)];
    } else {
        s = (int)eidx[e];
        d = (int)eidx[E + e];
    }
    src32[e] = s;
    dst32[e] = d;
    rel[e] = atomicAdd(&deg[d], 1);
}

// ---------------- prep: Wt[col][k] bf16 (+ Wa logit rows 128..135, zeros 136..143)
// Wtb layout: 144 rows x 128 cols of bf16.
//   rows 0..127 : Wt[col][k] = W[k][col]
//   rows 128+j  : j<4 -> (W @ att_src[j])^T ; j>=4 -> (W @ att_dst[j-4])^T
//   rows 136..143: zero
__global__ void k_prep(const float* __restrict__ W,
                       const float* __restrict__ att_src, const float* __restrict__ att_dst,
                       unsigned short* __restrict__ Wtb) {
    int b = blockIdx.x, t = threadIdx.x;
    if (b < 64) {
        int id = b * 256 + t;        // 0..16383
        int k = id >> 7, col = id & 127;
        Wtb[col * 128 + k] = f2bf(W[id]);
    } else {
        int k4 = t >> 3, j = t & 7;  // k4: 0..31
        const float* att = (j < 4) ? att_src : att_dst;
        int h = j & 3;
        #pragma unroll
        for (int kk = 0; kk < 4; kk++) {
            int k = k4 * 4 + kk;
            float s = 0.f;
            #pragma unroll
            for (int c = 0; c < 32; c++)
                s = fmaf(W[k * 128 + h * 32 + c], att[h * 32 + c], s);
            Wtb[(128 + j) * 128 + k] = f2bf(s);
        }
        for (int idx = t; idx < 1024; idx += 256)
            Wtb[(136 + (idx >> 7)) * 128 + (idx & 127)] = 0;
    }
}

// ---------------- MFMA GEMM: h(bf16) = x @ W, logits fused via Wa columns ----------
// 64 rows/block, 4 waves x 16 rows, mfma_f32_16x16x32_bf16.
// LDS: x tile 64x128 bf16 (16KB) + Wt 144x128 bf16 (36KB), both XOR-swizzled
// (elem ^= (row&7)<<3) for conflict-even ds_read_b128.
__global__ __launch_bounds__(256)
void k_gemm(const float* __restrict__ x, const unsigned short* __restrict__ Wtb,
            unsigned short* __restrict__ hb,
            float* __restrict__ a_src, float* __restrict__ a_dst, int N) {
    __shared__ unsigned short xlds[64 * 128];    // 16 KB
    __shared__ unsigned short wlds[144 * 128];   // 36 KB

    int t = threadIdx.x;
    int l = t & 63, w = t >> 6;
    int br = blockIdx.x * 64;

    // stage Wt (+Wa +zeros): 2304 16B units, swizzled reg->LDS
    #pragma unroll
    for (int i = 0; i < 9; i++) {
        int u = t + i * 256;
        uint4 v = *(const uint4*)(Wtb + u * 8);
        int row = u >> 4;
        int e8  = (u & 15) * 8;
        *(uint4*)&wlds[row * 128 + (e8 ^ ((row & 7) << 3))] = v;
    }
    // stage x tile: 4 threads/row, 32 f32 each -> bf16
    {
        int row = t >> 2, kq = t & 3;
        int gr = br + row;
        const float* xp = x + (size_t)gr * 128 + kq * 32;
        #pragma unroll
        for (int j = 0; j < 4; j++) {
            uint4 pk = make_uint4(0u, 0u, 0u, 0u);
            if (gr < N) {
                float4 v0 = *(const float4*)(xp + j * 8);
                float4 v1 = *(const float4*)(xp + j * 8 + 4);
                pk.x = pk2bf(v0.x, v0.y); pk.y = pk2bf(v0.z, v0.w);
                pk.z = pk2bf(v1.x, v1.y); pk.w = pk2bf(v1.z, v1.w);
            }
            int e8 = kq * 32 + j * 8;
            *(uint4*)&xlds[row * 128 + (e8 ^ ((row & 7) << 3))] = pk;
        }
    }
    __syncthreads();

    // A fragments: row = w*16 + (l&15), k = kc*32 + (l>>4)*8 + j
    bf16x8 a[4];
    int arow = w * 16 + (l & 15);
    int ae   = (l >> 4) * 8;
    #pragma unroll
    for (int kc = 0; kc < 4; kc++)
        a[kc] = *(const bf16x8*)&xlds[arow * 128 + ((kc * 32 + ae) ^ ((arow & 7) << 3))];

    int rowbase = br + w * 16 + (l >> 4) * 4;

    #pragma unroll
    for (int nb = 0; nb < 9; nb++) {
        int brow = nb * 16 + (l & 15);
        f32x4 c = {0.f, 0.f, 0.f, 0.f};
        #pragma unroll
        for (int kc = 0; kc < 4; kc++) {
            bf16x8 bfr = *(const bf16x8*)&wlds[brow * 128 + ((kc * 32 + ae) ^ ((brow & 7) << 3))];
            c = __builtin_amdgcn_mfma_f32_16x16x32_bf16(a[kc], bfr, c, 0, 0, 0);
        }
        if (nb < 8) {
            // h store: pack col pairs (c0 even from lane l, c0+1 from l^1)
            #pragma unroll
            for (int r = 0; r < 4; r++) {
                float v  = c[r];
                float vo = __shfl_xor(v, 1);
                int row = rowbase + r;
                if (row < N && (l & 1) == 0)
                    *(unsigned int*)&hb[(size_t)row * 128 + nb * 16 + (l & 15)] = pk2bf(v, vo);
            }
        } else {
            // logits: col j<4 -> a_src head j; 4<=j<8 -> a_dst head j-4
            int j = l & 15;
            #pragma unroll
            for (int r = 0; r < 4; r++) {
                int row = rowbase + r;
                if (row < N && j < 8) {
                    if (j < 4) a_src[row * 4 + j]     = c[r];
                    else       a_dst[row * 4 + j - 4] = c[r];
                }
            }
        }
    }
}

// ---------------- exclusive scan of deg -> row ----------------
__global__ __launch_bounds__(256)
void k_scan1(const int* __restrict__ deg, int* __restrict__ row,
             int* __restrict__ bsum, int N) {
    __shared__ int ts[256];
    int t = threadIdx.x;
    int base = blockIdx.x * 1024 + t * 4;
    int v0 = (base + 0 < N) ? deg[base + 0] : 0;
    int v1 = (base + 1 < N) ? deg[base + 1] : 0;
    int v2 = (base + 2 < N) ? deg[base + 2] : 0;
    int v3 = (base + 3 < N) ? deg[base + 3] : 0;
    int s = v0 + v1 + v2 + v3;
    ts[t] = s;
    __syncthreads();
    #pragma unroll
    for (int off = 1; off < 256; off <<= 1) {
        int u = (t >= off) ? ts[t - off] : 0;
        __syncthreads();
        ts[t] += u;
        __syncthreads();
    }
    int excl = ts[t] - s;
    if (t == 255) bsum[blockIdx.x] = ts[255];
    if (base + 0 < N) row[base + 0] = excl;
    if (base + 1 < N) row[base + 1] = excl + v0;
    if (base + 2 < N) row[base + 2] = excl + v0 + v1;
    if (base + 3 < N) row[base + 3] = excl + v0 + v1 + v2;
}

__global__ void k_scan2(int* __restrict__ bsum, int nb) {
    int t = threadIdx.x;
    int v = (t < nb) ? bsum[t] : 0;
    int orig = v;
    #pragma unroll
    for (int off = 1; off < 64; off <<= 1) {
        int u = __shfl_up(v, off);
        if (t >= off) v += u;
    }
    if (t < nb) bsum[t] = v - orig;
}

__global__ void k_scan3(int* __restrict__ row, const int* __restrict__ bsum, int N) {
    int i = blockIdx.x * blockDim.x + threadIdx.x;
    if (i >= N) return;
    row[i] += bsum[i >> 10];
}

// ---------------- bucket fill (no atomics) ----------------
__global__ void k_fill(const int* __restrict__ src32, const int* __restrict__ dst32,
                       const int* __restrict__ rel, const int* __restrict__ row,
                       int* __restrict__ bsrc, int E) {
    int e = blockIdx.x * blockDim.x + threadIdx.x;
    if (e >= E) return;
    bsrc[row[dst32[e]] + rel[e]] = src32[e];
}

// ---------------- fused gather aggregation: one wave per dst node ----------------
__global__ __launch_bounds__(256)
void k_aggregate(const int* __restrict__ bsrc, const int* __restrict__ row,
                 const int* __restrict__ deg,
                 const float* __restrict__ a_src, const float* __restrict__ a_dst,
                 const unsigned short* __restrict__ hb,
                 const float* __restrict__ bias,
                 float* __restrict__ out, int N) {
    int wave = threadIdx.x >> 6;
    int lane = threadIdx.x & 63;
    int d = blockIdx.x * 4 + wave;
    if (d >= N) return;
    int c0 = lane * 2;
    int head = lane >> 4;

    float ad = a_dst[d * 4 + head];

    float es = a_src[d * 4 + head] + ad;
    es = (es >= 0.f) ? es : NEG_SLOPE * es;
    float wself = __expf(es);
    unsigned int hp = *(const unsigned int*)&hb[(size_t)d * 128 + c0];
    float accx = wself * bf_lo(hp);
    float accy = wself * bf_hi(hp);
    float den  = wself;

    int start = row[d];
    int end   = start + deg[d];
    int j = start;
    for (; j + 3 < end; j += 4) {
        int s0 = bsrc[j + 0];
        int s1 = bsrc[j + 1];
        int s2 = bsrc[j + 2];
        int s3 = bsrc[j + 3];
        float as0 = a_src[s0 * 4 + head];
        float as1 = a_src[s1 * 4 + head];
        float as2 = a_src[s2 * 4 + head];
        float as3 = a_src[s3 * 4 + head];
        unsigned int p0 = *(const unsigned int*)&hb[(size_t)s0 * 128 + c0];
        unsigned int p1 = *(const unsigned int*)&hb[(size_t)s1 * 128 + c0];
        unsigned int p2 = *(const unsigned int*)&hb[(size_t)s2 * 128 + c0];
        unsigned int p3 = *(const unsigned int*)&hb[(size_t)s3 * 128 + c0];
        float e0 = as0 + ad; e0 = (e0 >= 0.f) ? e0 : NEG_SLOPE * e0;
        float e1 = as1 + ad; e1 = (e1 >= 0.f) ? e1 : NEG_SLOPE * e1;
        float e2 = as2 + ad; e2 = (e2 >= 0.f) ? e2 : NEG_SLOPE * e2;
        float e3 = as3 + ad; e3 = (e3 >= 0.f) ? e3 : NEG_SLOPE * e3;
        float w0 = __expf(e0), w1 = __expf(e1), w2 = __expf(e2), w3 = __expf(e3);
        den += (w0 + w1) + (w2 + w3);
        accx = fmaf(w0, bf_lo(p0), accx);
        accy = fmaf(w0, bf_hi(p0), accy);
        accx = fmaf(w1, bf_lo(p1), accx);
        accy = fmaf(w1, bf_hi(p1), accy);
        accx = fmaf(w2, bf_lo(p2), accx);
        accy = fmaf(w2, bf_hi(p2), accy);
        accx = fmaf(w3, bf_lo(p3), accx);
        accy = fmaf(w3, bf_hi(p3), accy);
    }
    for (; j < end; j++) {
        int s0 = bsrc[j];
        float as0 = a_src[s0 * 4 + head];
        unsigned int p0 = *(const unsigned int*)&hb[(size_t)s0 * 128 + c0];
        float e0 = as0 + ad; e0 = (e0 >= 0.f) ? e0 : NEG_SLOPE * e0;
        float w0 = __expf(e0);
        den += w0;
        accx = fmaf(w0, bf_lo(p0), accx);
        accy = fmaf(w0, bf_hi(p0), accy);
    }

    float rden = 1.f / (den + EPS_F);
    float2 b2 = *(const float2*)&bias[c0];
    float ox = fmaxf(accx * rden + b2.x, 0.f);
    float oy = fmaxf(accy * rden + b2.y, 0.f);
    *(float2*)&out[(size_t)d * 128 + c0] = make_float2(ox, oy);
}

extern "C" void kernel_launch(void* const* d_in, const int* in_sizes, int n_in,
                              void* d_out, int out_size, void* d_ws, size_t ws_size,
                              hipStream_t stream) {
    const float* x        = (const float*)d_in[0];
    const unsigned int* e = (const unsigned int*)d_in[1];
    const float* W        = (const float*)d_in[2];
    const float* att_src  = (const float*)d_in[3];
    const float* att_dst  = (const float*)d_in[4];
    const float* bias     = (const float*)d_in[5];
    float* out            = (float*)d_out;

    int N = in_sizes[0] / 128;
    int E = in_sizes[1] / 2;

    char* ws = (char*)d_ws;
    size_t off = 0;
    int*            flag  = (int*)(ws + off);            off += 256;
    int*            src32 = (int*)(ws + off);            off += (size_t)E * 4;
    int*            dst32 = (int*)(ws + off);            off += (size_t)E * 4;
    int*            rel   = (int*)(ws + off);            off += (size_t)E * 4;
    unsigned short* Wtb   = (unsigned short*)(ws + off); off += 144 * 128 * 2;
    unsigned short* hb    = (unsigned short*)(ws + off); off += (size_t)N * 128 * 2;
    float*          a_src = (float*)(ws + off);          off += (size_t)N * 16;
    float*          a_dst = (float*)(ws + off);          off += (size_t)N * 16;
    int*            deg   = (int*)(ws + off);            off += (size_t)N * 4;
    int*            row   = (int*)(ws + off);            off += (size_t)N * 4;
    int*            bsum  = (int*)(ws + off);            off += 4096;
    int*            bsrc  = (int*)(ws + off);            off += (size_t)E * 4;

    int nb = (N + 1023) / 1024;

    hipMemsetAsync(deg, 0, (size_t)N * 4, stream);

    k_detect<<<1, 64, 0, stream>>>(e, flag);
    k_convert_hist<<<(E + 255) / 256, 256, 0, stream>>>(e, flag, src32, dst32, rel, deg, E);
    k_prep<<<65, 256, 0, stream>>>(W, att_src, att_dst, Wtb);
    k_gemm<<<(N + 63) / 64, 256, 0, stream>>>(x, Wtb, hb, a_src, a_dst, N);
    k_scan1<<<nb, 256, 0, stream>>>(deg, row, bsum, N);
    k_scan2<<<1, 64, 0, stream>>>(bsum, nb);
    k_scan3<<<(N + 255) / 256, 256, 0, stream>>>(row, bsum, N);
    k_fill<<<(E + 255) / 256, 256, 0, stream>>>(src32, dst32, rel, row, bsrc, E);
    k_aggregate<<<(N + 3) / 4, 256, 0, stream>>>(bsrc, row, deg, a_src, a_dst, hb, bias, out, N);
}